// Round 8
// baseline (1051.738 us; speedup 1.0000x reference)
//
#include <hip/hip_runtime.h>
#include <hip/hip_bf16.h>

// B=2, S=2048, W=32, D=1024, H=16, hd=64
// Pipeline (full path):
//   bf16-cast: Wq,Wk,Wv,Wo,q (small only)
//   K/V GEMM: gemm_big = round-0 skeleton (256x256, BK=32, 4-slot LDS ring,
//             one barrier/K-tile, T2 chunk-XOR swizzle, T5 setprio, T1 XCD
//             map) + fused fp32->bf16 A-cast, round-8 schedule:
//             - 3 rotating A-reg sets (sa/sb/sc): AISS A(t+5) at tile t,
//               CVT consumes the set issued 2 tiles ago (~1600cyc age).
//             - CVT at tile END (after MFMAs, SB0-pinned): its vmcnt wait
//               overlaps the sibling wave's MFMAs, not our own issue.
//             - STGB before AISS: CVT-at-u's wait (A-set(u-2)) drains
//               STGB(u-2)=B(u+1) -> B provably resident 1 tile early.
//               (round-7 order left B-residency to timing luck.)
//             - tail: vmcnt(0) at end of tiles NT-3..NT-2.
//   Q/O GEMM: gemm_lds (128x128)
//   attn: per (b,s') head-softmax gather-attention -> A (4096x1024 bf16)
//   out  = A@Wo^T+bo (fp32)

#define DEVI __device__ __forceinline__

typedef __attribute__((ext_vector_type(8))) short bf16x8;
typedef __attribute__((ext_vector_type(4))) float f32x4;
typedef const __attribute__((address_space(1))) void* gvp;
typedef __attribute__((address_space(3))) void* lvp;

DEVI ushort f2bf(float f) {
  uint u = __float_as_uint(f);
  u = u + 0x7fffu + ((u >> 16) & 1u);
  return (ushort)(u >> 16);
}
DEVI float bf2f(ushort u) { return __uint_as_float(((uint)u) << 16); }

// ---------------- elementwise fp32 -> bf16 cast (RNE), 8 elems/thread ----
__global__ __launch_bounds__(256) void cast_kernel(const float* __restrict__ in,
                                                   ushort* __restrict__ out,
                                                   long n) {
  long i = ((long)blockIdx.x * 256 + threadIdx.x) * 8;
  const long stride = (long)gridDim.x * 256 * 8;
  for (; i < n; i += stride) {
    float4 a = *reinterpret_cast<const float4*>(in + i);
    float4 b = *reinterpret_cast<const float4*>(in + i + 4);
    ushort o[8];
    o[0] = f2bf(a.x); o[1] = f2bf(a.y); o[2] = f2bf(a.z); o[3] = f2bf(a.w);
    o[4] = f2bf(b.x); o[5] = f2bf(b.y); o[6] = f2bf(b.z); o[7] = f2bf(b.w);
    *reinterpret_cast<int4*>(out + i) = *reinterpret_cast<const int4*>(o);
  }
}

// ---------------- fused-cast GEMM: C = A(fp32) @ W(bf16)^T + bias ---------
// Tile 256(M)x256(N), K=1024, BK=32, 32 K-tiles, 4-slot ring (A16K+B16K).
// Row = 64B = 4 chunks of 16B; stored chunk p of row r holds source chunk
// p^((r>>1)&3); fragment read swz ((lane>>4)^((lm>>1)&3))*16.
// Tile body: frag reads; STGB B(t+3); AISS A(t+5); MFMAs; CVT A(t+3)
// (set from t-2) -> slot t+3; [tail vmcnt(0)]; barrier.
__global__ __launch_bounds__(512)
__attribute__((amdgpu_waves_per_eu(2, 2)))
void gemm_big(const float* __restrict__ Ag, const ushort* __restrict__ Wg,
              const float* __restrict__ bias, ushort* __restrict__ Cg) {
  constexpr int K = 1024;
  constexpr int NT = 32;       // K-tiles of 32
  constexpr int SLOT = 32768;  // 16 KB A + 16 KB B
  __shared__ char lds[4 * SLOT];
  const int tid = threadIdx.x;
  const int lane = tid & 63;
  const int wave = tid >> 6;
  const int wm = wave >> 2;  // 0..1 (M half, 128 rows)
  const int wn = wave & 3;   // 0..3 (N quarter, 64 cols)
  const int d = blockIdx.x;
  const int bn = (d >> 3) & 3;
  const size_t bm = (size_t)(d & 7) * (gridDim.x >> 5) + (d >> 5);

  const ushort* bB = Wg + (size_t)bn * 256 * K;

  // staging: chunk f = tid (rows 0..127) and tid+512 (rows 128..255);
  // row = f>>2, source chunk c = (f&3)^((row>>1)&3) (same for row+128).
  const int ar0 = tid >> 2;
  const int ac0 = (tid & 3) ^ ((ar0 >> 1) & 3);
  const float* pA0 = Ag + bm * 256 * K + (size_t)ar0 * K + ac0 * 8;
  const float* pA1 = pA0 + (size_t)128 * K;
  const ushort* bS0 = bB + (size_t)ar0 * K + ac0 * 8;
  const ushort* bS1 = bB + (size_t)(ar0 + 128) * K + ac0 * 8;
  const int adst0 = tid * 16;
  const int adst1 = tid * 16 + 8192;
  const int bdst0 = 16384 + tid * 16;
  const int bdst1 = 24576 + tid * 16;

  // fragment-read lane-invariant offsets (round-0 verified)
  const int lm = lane & 15;
  const int cs = (lm >> 1) & 3;
  const int cSwz = ((lane >> 4) ^ cs) * 16;
  const int offA = lm * 64 + cSwz + wm * 8192;
  const int offB = 16384 + lm * 64 + cSwz + wn * 4096;
  const char* ldsc = (const char*)lds;

  f32x4 acc[8][4] = {};
  float4 sa[4], sb[4], sc[4];

#define SB0 __builtin_amdgcn_sched_barrier(0)
#define AISS4(set, ktE)                                           \
  {                                                               \
    set[0] = *reinterpret_cast<const float4*>(pA0 + (ktE));       \
    set[1] = *reinterpret_cast<const float4*>(pA0 + (ktE) + 4);   \
    set[2] = *reinterpret_cast<const float4*>(pA1 + (ktE));       \
    set[3] = *reinterpret_cast<const float4*>(pA1 + (ktE) + 4);   \
  }
#define CVT4(set, base)                                                          \
  {                                                                              \
    uint w0, w1, w2, w3;                                                         \
    asm("v_cvt_pk_bf16_f32 %0,%1,%2" : "=v"(w0) : "v"(set[0].x), "v"(set[0].y)); \
    asm("v_cvt_pk_bf16_f32 %0,%1,%2" : "=v"(w1) : "v"(set[0].z), "v"(set[0].w)); \
    asm("v_cvt_pk_bf16_f32 %0,%1,%2" : "=v"(w2) : "v"(set[1].x), "v"(set[1].y)); \
    asm("v_cvt_pk_bf16_f32 %0,%1,%2" : "=v"(w3) : "v"(set[1].z), "v"(set[1].w)); \
    *reinterpret_cast<uint4*>(lds + (base) + adst0) = make_uint4(w0, w1, w2, w3); \
    asm("v_cvt_pk_bf16_f32 %0,%1,%2" : "=v"(w0) : "v"(set[2].x), "v"(set[2].y)); \
    asm("v_cvt_pk_bf16_f32 %0,%1,%2" : "=v"(w1) : "v"(set[2].z), "v"(set[2].w)); \
    asm("v_cvt_pk_bf16_f32 %0,%1,%2" : "=v"(w2) : "v"(set[3].x), "v"(set[3].y)); \
    asm("v_cvt_pk_bf16_f32 %0,%1,%2" : "=v"(w3) : "v"(set[3].z), "v"(set[3].w)); \
    *reinterpret_cast<uint4*>(lds + (base) + adst1) = make_uint4(w0, w1, w2, w3); \
  }
#define STGB(ktE, base)                                                        \
  {                                                                            \
    __builtin_amdgcn_global_load_lds((gvp)(bS0 + (ktE)),                       \
                                     (lvp)(lds + (base) + bdst0), 16, 0, 0);   \
    __builtin_amdgcn_global_load_lds((gvp)(bS1 + (ktE)),                       \
                                     (lvp)(lds + (base) + bdst1), 16, 0, 0);   \
  }

  // ---- prologue: slots 0..2 staged; leave sa=A(3), sb=A(4) in flight ----
  AISS4(sa, 0);  SB0; CVT4(sa, 0 * SLOT); SB0;
  AISS4(sa, 32); SB0; CVT4(sa, 1 * SLOT); SB0;
  AISS4(sa, 64); SB0; CVT4(sa, 2 * SLOT); SB0;
  STGB(0, 0 * SLOT);
  STGB(32, 1 * SLOT);
  STGB(64, 2 * SLOT);
  AISS4(sa, 96);   // A(3), consumed at t=0
  AISS4(sb, 128);  // A(4), consumed at t=1
  SB0;
  // drain B(0) (oldest 2 of [B0(2),B1(2),B2(2),sa(4),sb(4)]=14)
  asm volatile("s_waitcnt vmcnt(12)" ::: "memory");
  asm volatile("s_waitcnt lgkmcnt(0)" ::: "memory");
  __builtin_amdgcn_s_barrier();
  SB0;

  int rdOff = 0, stOff = 3 * SLOT;

#define TILE(tt, CS, IS)                                                     \
  {                                                                          \
    const char* pA = ldsc + rdOff + offA;                                    \
    const char* pB = ldsc + rdOff + offB;                                    \
    bf16x8 a[8], b[4];                                                       \
    _Pragma("unroll") for (int fi = 0; fi < 8; ++fi)                         \
        a[fi] = *reinterpret_cast<const bf16x8*>(pA + fi * 1024);            \
    _Pragma("unroll") for (int fj = 0; fj < 4; ++fj)                         \
        b[fj] = *reinterpret_cast<const bf16x8*>(pB + fj * 1024);            \
    if ((tt) + 3 < NT) STGB(((tt) + 3) * 32, stOff);                         \
    if ((tt) + 5 < NT) AISS4(IS, ((tt) + 5) * 32);                           \
    SB0;                                                                     \
    __builtin_amdgcn_s_setprio(1);                                           \
    _Pragma("unroll") for (int fi = 0; fi < 8; ++fi)                         \
        _Pragma("unroll") for (int fj = 0; fj < 4; ++fj)                     \
            acc[fi][fj] = __builtin_amdgcn_mfma_f32_16x16x32_bf16(           \
                a[fi], b[fj], acc[fi][fj], 0, 0, 0);                         \
    __builtin_amdgcn_s_setprio(0);                                           \
    SB0;                                                                     \
    if ((tt) + 3 < NT) CVT4(CS, stOff);                                      \
    if ((tt) >= NT - 3 && (tt) < NT - 1) {                                   \
      SB0;                                                                   \
      asm volatile("s_waitcnt vmcnt(0)" ::: "memory");                       \
    }                                                                        \
    __builtin_amdgcn_s_barrier();                                            \
    rdOff = (rdOff == 3 * SLOT) ? 0 : rdOff + SLOT;                          \
    stOff = (stOff == 3 * SLOT) ? 0 : stOff + SLOT;                          \
  }

#pragma unroll 1
  for (int tb = 0; tb < 30; tb += 3) {
    TILE(tb, sa, sc);
    TILE(tb + 1, sb, sa);
    TILE(tb + 2, sc, sb);
  }
  TILE(30, sa, sc);
  TILE(31, sb, sa);
#undef TILE
#undef AISS4
#undef CVT4
#undef STGB
#undef SB0

  // ---- epilogue: C/D layout col=lane&15, row=(lane>>4)*4+r ----
#pragma unroll
  for (int fi = 0; fi < 8; ++fi) {
#pragma unroll
    for (int fj = 0; fj < 4; ++fj) {
      int n = bn * 256 + wn * 64 + fj * 16 + lm;
      float bv = bias[n];
#pragma unroll
      for (int r = 0; r < 4; ++r) {
        size_t m = bm * 256 + wm * 128 + fi * 16 + ((lane >> 4) * 4) + r;
        Cg[m * 1024 + n] = f2bf(acc[fi][fj][r] + bv);
      }
    }
  }
}

// ---------------- 128x128 gload_lds GEMM (Q/O; verified) -------------------
template <typename TOUT>
__global__ __launch_bounds__(256) void gemm_lds(const ushort* __restrict__ Ag,
                                                const ushort* __restrict__ Wg,
                                                const float* __restrict__ bias,
                                                TOUT* __restrict__ Cg) {
  constexpr int K = 1024;
  __shared__ ushort lA[128 * 64];
  __shared__ ushort lB[128 * 64];
  const int tid = threadIdx.x;
  const int lane = tid & 63;
  const int wave = tid >> 6;
  const int wr = (wave >> 1) * 64;
  const int wc = (wave & 1) * 64;
  const int d = blockIdx.x;
  const int bn = (d >> 3) & 7;
  const size_t bm = (size_t)(d & 7) * (gridDim.x >> 6) + (d >> 6);

  const ushort* aB = Ag + bm * 128 * K;
  const ushort* bB = Wg + (size_t)bn * 128 * K;
  const int srow = wave * 32 + (lane >> 3);
  const int scol = ((lane & 7) ^ (lane >> 3)) * 8;
  char* lAc = (char*)lA;
  char* lBc = (char*)lB;

  f32x4 acc[4][4] = {};

  for (int kt = 0; kt < K; kt += 64) {
    __syncthreads();
#pragma unroll
    for (int c = 0; c < 4; ++c) {
      __builtin_amdgcn_global_load_lds(
          (gvp)(aB + (size_t)(srow + c * 8) * K + kt + scol),
          (lvp)(lAc + wave * 4096 + c * 1024), 16, 0, 0);
      __builtin_amdgcn_global_load_lds(
          (gvp)(bB + (size_t)(srow + c * 8) * K + kt + scol),
          (lvp)(lBc + wave * 4096 + c * 1024), 16, 0, 0);
    }
    __syncthreads();
#pragma unroll
    for (int kk = 0; kk < 2; ++kk) {
      bf16x8 af[4], bg[4];
#pragma unroll
      for (int fi = 0; fi < 4; ++fi) {
        int r = wr + fi * 16 + (lane & 15);
        int byte = (r * 128 + kk * 64 + ((lane >> 4) * 16)) ^ ((r & 7) << 4);
        af[fi] = *reinterpret_cast<const bf16x8*>(lAc + byte);
      }
#pragma unroll
      for (int fj = 0; fj < 4; ++fj) {
        int r = wc + fj * 16 + (lane & 15);
        int byte = (r * 128 + kk * 64 + ((lane >> 4) * 16)) ^ ((r & 7) << 4);
        bg[fj] = *reinterpret_cast<const bf16x8*>(lBc + byte);
      }
#pragma unroll
      for (int fi = 0; fi < 4; ++fi)
#pragma unroll
        for (int fj = 0; fj < 4; ++fj)
          acc[fi][fj] = __builtin_amdgcn_mfma_f32_16x16x32_bf16(af[fi], bg[fj],
                                                                acc[fi][fj], 0, 0, 0);
    }
  }
#pragma unroll
  for (int fi = 0; fi < 4; ++fi) {
#pragma unroll
    for (int fj = 0; fj < 4; ++fj) {
      int n = bn * 128 + wc + fj * 16 + (lane & 15);
      float bv = bias[n];
#pragma unroll
      for (int r = 0; r < 4; ++r) {
        size_t m = bm * 128 + wr + fi * 16 + ((lane >> 4) * 4) + r;
        float val = acc[fi][fj][r] + bv;
        if constexpr (sizeof(TOUT) == 2)
          reinterpret_cast<ushort*>(Cg)[m * 1024 + n] = f2bf(val);
        else
          reinterpret_cast<float*>(Cg)[m * 1024 + n] = val;
      }
    }
  }
}

// ------------- reg-staged GEMM (fp32 A): fallback path only ---------------
template <typename TIN, typename TOUT>
__global__ __launch_bounds__(256) void gemm_bias(const TIN* __restrict__ Ag,
                                                 const float* __restrict__ Wg,
                                                 const float* __restrict__ bias,
                                                 TOUT* __restrict__ Cg) {
  constexpr int K = 1024;
  __shared__ char lA[128 * 64 * 2];
  __shared__ char lB[128 * 64 * 2];
  const int tid = threadIdx.x;
  const int lane = tid & 63;
  const int wave = tid >> 6;
  const int wr = (wave >> 1) * 64;
  const int wc = (wave & 1) * 64;
  const int bn = blockIdx.x;
  const size_t bm = blockIdx.y;

  const TIN* aBase = Ag + bm * 128 * K;
  const float* bBase = Wg + (size_t)bn * 128 * K;

  f32x4 acc[4][4] = {};

  for (int kt = 0; kt < K; kt += 64) {
    __syncthreads();
    if constexpr (sizeof(TIN) == 4) {
#pragma unroll
      for (int i = 0; i < 8; ++i) {
        int f = tid + i * 256;
        int row = f >> 4, c4 = f & 15;
        const float4 v = *reinterpret_cast<const float4*>(
            reinterpret_cast<const float*>(aBase) + (size_t)row * K + kt + c4 * 4);
        ushort4 pk;
        pk.x = f2bf(v.x); pk.y = f2bf(v.y); pk.z = f2bf(v.z); pk.w = f2bf(v.w);
        int byte = (row * 128 + c4 * 8) ^ ((row & 7) << 4);
        *reinterpret_cast<ushort4*>(lA + byte) = pk;
      }
    } else {
#pragma unroll
      for (int i = 0; i < 4; ++i) {
        int f = tid + i * 256;
        int row = f >> 3, c8 = f & 7;
        int4 v = *reinterpret_cast<const int4*>(
            reinterpret_cast<const ushort*>(aBase) + (size_t)row * K + kt + c8 * 8);
        int byte = (row * 128 + c8 * 16) ^ ((row & 7) << 4);
        *reinterpret_cast<int4*>(lA + byte) = v;
      }
    }
#pragma unroll
    for (int i = 0; i < 8; ++i) {
      int f = tid + i * 256;
      int row = f >> 4, c4 = f & 15;
      const float4 v =
          *reinterpret_cast<const float4*>(bBase + (size_t)row * K + kt + c4 * 4);
      ushort4 pk;
      pk.x = f2bf(v.x); pk.y = f2bf(v.y); pk.z = f2bf(v.z); pk.w = f2bf(v.w);
      int byte = (row * 128 + c4 * 8) ^ ((row & 7) << 4);
      *reinterpret_cast<ushort4*>(lB + byte) = pk;
    }
    __syncthreads();
#pragma unroll
    for (int kk = 0; kk < 2; ++kk) {
      bf16x8 af[4], bg[4];
#pragma unroll
      for (int fi = 0; fi < 4; ++fi) {
        int r = wr + fi * 16 + (lane & 15);
        int byte = (r * 128 + kk * 64 + ((lane >> 4) * 16)) ^ ((r & 7) << 4);
        af[fi] = *reinterpret_cast<const bf16x8*>(lA + byte);
      }
#pragma unroll
      for (int fj = 0; fj < 4; ++fj) {
        int r = wc + fj * 16 + (lane & 15);
        int byte = (r * 128 + kk * 64 + ((lane >> 4) * 16)) ^ ((r & 7) << 4);
        bg[fj] = *reinterpret_cast<const bf16x8*>(lB + byte);
      }
#pragma unroll
      for (int fi = 0; fi < 4; ++fi)
#pragma unroll
        for (int fj = 0; fj < 4; ++fj)
          acc[fi][fj] =
              __builtin_amdgcn_mfma_f32_16x16x32_bf16(af[fi], bg[fj], acc[fi][fj], 0, 0, 0);
    }
  }
#pragma unroll
  for (int fi = 0; fi < 4; ++fi) {
#pragma unroll
    for (int fj = 0; fj < 4; ++fj) {
      int n = bn * 128 + wc + fj * 16 + (lane & 15);
      float bv = bias[n];
#pragma unroll
      for (int r = 0; r < 4; ++r) {
        size_t m = bm * 128 + wr + fi * 16 + ((lane >> 4) * 4) + r;
        float val = acc[fi][fj][r] + bv;
        if constexpr (sizeof(TOUT) == 2)
          reinterpret_cast<ushort*>(Cg)[m * 1024 + n] = f2bf(val);
        else
          reinterpret_cast<float*>(Cg)[m * 1024 + n] = val;
      }
    }
  }
}

// ---------------- attention: one block per (b,s'), head-axis softmax ------
__global__ __launch_bounds__(512) void attn_kernel(const ushort* __restrict__ Q,
                                                   const ushort* __restrict__ Kl,
                                                   const ushort* __restrict__ Vl,
                                                   ushort* __restrict__ Aout) {
  const int bs = blockIdx.x;
  const int b = bs >> 11, sp = bs & 2047;
  const int tid = threadIdx.x;
  const int wave = tid >> 6, lane = tid & 63;

  __shared__ ushort qrow[1024];
  __shared__ float sc[16][32];
  __shared__ float attnw[16][32];
  __shared__ float mx[32], rinv[32];

  reinterpret_cast<uint*>(qrow)[tid] =
      reinterpret_cast<const uint*>(Q + (size_t)bs * 1024)[tid];
  __syncthreads();

  const int wp = lane & 31, half = lane >> 5;
#pragma unroll
  for (int hh = 0; hh < 2; ++hh) {
    const int h = wave * 2 + hh;
    const int s_k = h * 128 + (sp >> 4);
    const int w_k = (sp & 15) * 2 + (wp >> 4);
    const ushort* kp =
        Kl + (((size_t)(b * 2048 + s_k) * 32) + w_k) * 1024 + (wp & 15) * 64 + half * 32;
    const ushort* qp = qrow + h * 64 + half * 32;
    float dot = 0.f;
#pragma unroll
    for (int j = 0; j < 32; j += 8) {
      int4 kv = *reinterpret_cast<const int4*>(kp + j);
      int4 qv = *reinterpret_cast<const int4*>(qp + j);
      const ushort* ka = reinterpret_cast<const ushort*>(&kv);
      const ushort* qa = reinterpret_cast<const ushort*>(&qv);
#pragma unroll
      for (int t = 0; t < 8; ++t) dot += bf2f(ka[t]) * bf2f(qa[t]);
    }
    dot += __shfl_xor(dot, 32);
    if (half == 0) sc[h][wp] = dot * 0.125f;
  }
  __syncthreads();
  if (tid < 32) {
    float m = sc[0][tid];
#pragma unroll
    for (int h = 1; h < 16; ++h) m = fmaxf(m, sc[h][tid]);
    float s = 0.f;
#pragma unroll
    for (int h = 0; h < 16; ++h) s += __expf(sc[h][tid] - m);
    mx[tid] = m;
    rinv[tid] = 1.f / s;
  }
  __syncthreads();
  if (lane < 32) {
#pragma unroll
    for (int hh = 0; hh < 2; ++hh) {
      const int h = wave * 2 + hh;
      attnw[h][lane] = __expf(sc[h][lane] - mx[lane]) * rinv[lane];
    }
  }
  __syncthreads();
#pragma unroll
  for (int hh = 0; hh < 2; ++hh) {
    const int h = wave * 2 + hh;
    const int s_k = h * 128 + (sp >> 4);
    const size_t vb = (((size_t)(b * 2048 + s_k) * 32) + (sp & 15) * 2) * 1024;
    float a = 0.f;
#pragma unroll
    for (int w2 = 0; w2 < 32; ++w2) {
      float wgt = attnw[h][w2];
      a += wgt * bf2f(Vl[vb + (size_t)(w2 >> 4) * 1024 + (w2 & 15) * 64 + lane]);
    }
    Aout[(((size_t)(b * 16 + h)) * 2048 + sp) * 64 + lane] = f2bf(a);
  }
}

extern "C" void kernel_launch(void* const* d_in, const int* in_sizes, int n_in,
                              void* d_out, int out_size, void* d_ws, size_t ws_size,
                              hipStream_t stream) {
  const float* q = (const float*)d_in[0];
  const float* k = (const float*)d_in[1];
  const float* v = (const float*)d_in[2];
  const float* Wq = (const float*)d_in[3];
  const float* bq = (const float*)d_in[4];
  const float* Wk = (const float*)d_in[5];
  const float* bk = (const float*)d_in[6];
  const float* Wv = (const float*)d_in[7];
  const float* bv = (const float*)d_in[8];
  const float* Wo = (const float*)d_in[9];
  const float* bo = (const float*)d_in[10];
  float* out = (float*)d_out;

  char* ws = (char*)d_ws;
  const size_t MB = 1u << 20;
  ushort* Qlin = (ushort*)ws;                    // 8 MiB
  ushort* Aws  = (ushort*)(ws + 8 * MB);         // 8 MiB
  ushort* wkbf = (ushort*)(ws + 16 * MB);        // 2 MiB
  ushort* wvbf = (ushort*)(ws + 18 * MB);        // 2 MiB
  ushort* wqbf = (ushort*)(ws + 20 * MB);        // 2 MiB
  ushort* wobf = (ushort*)(ws + 22 * MB);        // 2 MiB
  ushort* qbf  = (ushort*)(ws + 24 * MB);        // 8 MiB
  ushort* Klin = (ushort*)(ws + 32 * MB);        // 256 MiB
  ushort* Vlin = (ushort*)(ws + 288 * MB);       // 256 MiB
  const bool full = ws_size >= 800 * MB;

  if (full) {
    cast_kernel<<<dim3(512), 256, 0, stream>>>(Wq, wqbf, 1048576L);
    cast_kernel<<<dim3(512), 256, 0, stream>>>(Wk, wkbf, 1048576L);
    cast_kernel<<<dim3(512), 256, 0, stream>>>(Wv, wvbf, 1048576L);
    cast_kernel<<<dim3(512), 256, 0, stream>>>(Wo, wobf, 1048576L);
    cast_kernel<<<dim3(2048), 256, 0, stream>>>(q, qbf, 4194304L);
    gemm_lds<ushort><<<dim3(256), 256, 0, stream>>>(qbf, wqbf, bq, Qlin);
    gemm_big<<<dim3(2048), 512, 0, stream>>>(k, wkbf, bk, Klin);
    gemm_big<<<dim3(2048), 512, 0, stream>>>(v, wvbf, bv, Vlin);
    attn_kernel<<<dim3(4096), dim3(512), 0, stream>>>(Qlin, Klin, Vlin, Aws);
    gemm_lds<float><<<dim3(256), 256, 0, stream>>>(Aws, wobf, bo, out);
  } else {
    gemm_bias<float, ushort><<<dim3(8, 32), 256, 0, stream>>>(q, Wq, bq, Qlin);
    gemm_bias<float, ushort><<<dim3(8, 1024), 256, 0, stream>>>(k, Wk, bk, Klin);
    gemm_bias<float, ushort><<<dim3(8, 1024), 256, 0, stream>>>(v, Wv, bv, Vlin);
    attn_kernel<<<dim3(4096), dim3(512), 0, stream>>>(Qlin, Klin, Vlin, Aws);
    gemm_bias<ushort, float><<<dim3(8, 32), 256, 0, stream>>>(Aws, Wo, bo, out);
  }
}

// Round 9
// 969.194 us; speedup vs baseline: 1.0852x; 1.0852x over previous
//
#include <hip/hip_runtime.h>
#include <hip/hip_bf16.h>

// B=2, S=2048, W=32, D=1024, H=16, hd=64
// Pipeline (full path):
//   bf16-cast: Wq,Wk,Wv,Wo,q (small only)
//   K/V GEMM: gemm_big = round-0 skeleton (256x256, BK=32, 4-slot LDS ring,
//             one barrier/K-tile, T2 chunk-XOR swizzle, T5 setprio, T1 XCD
//             map) + fused fp32->bf16 A-cast, round-9 schedule:
//             - CVT at tile TOP (round-7 position, proven 417us) but with
//               2 rotating A-reg sets (sa even / sb odd): AISS at t issues
//               A(t+5); CVT at t consumes the set issued at t-2 (~2400cyc
//               age >> ~900cyc HBM latency) -> the top-of-tile wait is free.
//               (round-7's 1-set gave 1-tile age -> ~500cyc stall/tile;
//               round-8's CVT-at-end serialized after MFMAs -> regressed.)
//             - STGB before AISS: CVT-at-t's wait (A-set from t-2) drains
//               STGB B(t+1) issued at t-2 -> B provably drained one barrier
//               before its reads (drain top-of-t, barrier end-of-t, read t+1).
//             - tail: vmcnt(0) at end of tiles NT-3..NT-2 covers B(30),B(31).
//   Q/O GEMM: gemm_lds (128x128)
//   attn: per (b,s') head-softmax gather-attention -> A (4096x1024 bf16)
//   out  = A@Wo^T+bo (fp32)

#define DEVI __device__ __forceinline__

typedef __attribute__((ext_vector_type(8))) short bf16x8;
typedef __attribute__((ext_vector_type(4))) float f32x4;
typedef const __attribute__((address_space(1))) void* gvp;
typedef __attribute__((address_space(3))) void* lvp;

DEVI ushort f2bf(float f) {
  uint u = __float_as_uint(f);
  u = u + 0x7fffu + ((u >> 16) & 1u);
  return (ushort)(u >> 16);
}
DEVI float bf2f(ushort u) { return __uint_as_float(((uint)u) << 16); }

// ---------------- elementwise fp32 -> bf16 cast (RNE), 8 elems/thread ----
__global__ __launch_bounds__(256) void cast_kernel(const float* __restrict__ in,
                                                   ushort* __restrict__ out,
                                                   long n) {
  long i = ((long)blockIdx.x * 256 + threadIdx.x) * 8;
  const long stride = (long)gridDim.x * 256 * 8;
  for (; i < n; i += stride) {
    float4 a = *reinterpret_cast<const float4*>(in + i);
    float4 b = *reinterpret_cast<const float4*>(in + i + 4);
    ushort o[8];
    o[0] = f2bf(a.x); o[1] = f2bf(a.y); o[2] = f2bf(a.z); o[3] = f2bf(a.w);
    o[4] = f2bf(b.x); o[5] = f2bf(b.y); o[6] = f2bf(b.z); o[7] = f2bf(b.w);
    *reinterpret_cast<int4*>(out + i) = *reinterpret_cast<const int4*>(o);
  }
}

// ---------------- fused-cast GEMM: C = A(fp32) @ W(bf16)^T + bias ---------
// Tile 256(M)x256(N), K=1024, BK=32, 32 K-tiles, 4-slot ring (A16K+B16K).
// Row = 64B = 4 chunks of 16B; stored chunk p of row r holds source chunk
// p^((r>>1)&3); fragment read swz ((lane>>4)^((lm>>1)&3))*16.
// Tile body: CVT A(t+3) (set from t-2) -> slot t+3; STGB B(t+3);
// AISS A(t+5) (same set, just freed); frag reads slot t; 32 MFMA;
// [tail vmcnt(0)]; barrier.
__global__ __launch_bounds__(512)
__attribute__((amdgpu_waves_per_eu(2, 2)))
void gemm_big(const float* __restrict__ Ag, const ushort* __restrict__ Wg,
              const float* __restrict__ bias, ushort* __restrict__ Cg) {
  constexpr int K = 1024;
  constexpr int NT = 32;       // K-tiles of 32
  constexpr int SLOT = 32768;  // 16 KB A + 16 KB B
  __shared__ char lds[4 * SLOT];
  const int tid = threadIdx.x;
  const int lane = tid & 63;
  const int wave = tid >> 6;
  const int wm = wave >> 2;  // 0..1 (M half, 128 rows)
  const int wn = wave & 3;   // 0..3 (N quarter, 64 cols)
  const int d = blockIdx.x;
  const int bn = (d >> 3) & 3;
  const size_t bm = (size_t)(d & 7) * (gridDim.x >> 5) + (d >> 5);

  const ushort* bB = Wg + (size_t)bn * 256 * K;

  // staging: chunk f = tid (rows 0..127) and tid+512 (rows 128..255);
  // row = f>>2, source chunk c = (f&3)^((row>>1)&3) (same for row+128).
  const int ar0 = tid >> 2;
  const int ac0 = (tid & 3) ^ ((ar0 >> 1) & 3);
  const float* pA0 = Ag + bm * 256 * K + (size_t)ar0 * K + ac0 * 8;
  const float* pA1 = pA0 + (size_t)128 * K;
  const ushort* bS0 = bB + (size_t)ar0 * K + ac0 * 8;
  const ushort* bS1 = bB + (size_t)(ar0 + 128) * K + ac0 * 8;
  const int adst0 = tid * 16;
  const int adst1 = tid * 16 + 8192;
  const int bdst0 = 16384 + tid * 16;
  const int bdst1 = 24576 + tid * 16;

  // fragment-read lane-invariant offsets (round-0 verified)
  const int lm = lane & 15;
  const int cs = (lm >> 1) & 3;
  const int cSwz = ((lane >> 4) ^ cs) * 16;
  const int offA = lm * 64 + cSwz + wm * 8192;
  const int offB = 16384 + lm * 64 + cSwz + wn * 4096;
  const char* ldsc = (const char*)lds;

  f32x4 acc[8][4] = {};
  float4 sa[4], sb[4];

#define SB0 __builtin_amdgcn_sched_barrier(0)
#define AISS4(set, ktE)                                           \
  {                                                               \
    set[0] = *reinterpret_cast<const float4*>(pA0 + (ktE));       \
    set[1] = *reinterpret_cast<const float4*>(pA0 + (ktE) + 4);   \
    set[2] = *reinterpret_cast<const float4*>(pA1 + (ktE));       \
    set[3] = *reinterpret_cast<const float4*>(pA1 + (ktE) + 4);   \
  }
#define CVT4(set, base)                                                          \
  {                                                                              \
    uint w0, w1, w2, w3;                                                         \
    asm("v_cvt_pk_bf16_f32 %0,%1,%2" : "=v"(w0) : "v"(set[0].x), "v"(set[0].y)); \
    asm("v_cvt_pk_bf16_f32 %0,%1,%2" : "=v"(w1) : "v"(set[0].z), "v"(set[0].w)); \
    asm("v_cvt_pk_bf16_f32 %0,%1,%2" : "=v"(w2) : "v"(set[1].x), "v"(set[1].y)); \
    asm("v_cvt_pk_bf16_f32 %0,%1,%2" : "=v"(w3) : "v"(set[1].z), "v"(set[1].w)); \
    *reinterpret_cast<uint4*>(lds + (base) + adst0) = make_uint4(w0, w1, w2, w3); \
    asm("v_cvt_pk_bf16_f32 %0,%1,%2" : "=v"(w0) : "v"(set[2].x), "v"(set[2].y)); \
    asm("v_cvt_pk_bf16_f32 %0,%1,%2" : "=v"(w1) : "v"(set[2].z), "v"(set[2].w)); \
    asm("v_cvt_pk_bf16_f32 %0,%1,%2" : "=v"(w2) : "v"(set[3].x), "v"(set[3].y)); \
    asm("v_cvt_pk_bf16_f32 %0,%1,%2" : "=v"(w3) : "v"(set[3].z), "v"(set[3].w)); \
    *reinterpret_cast<uint4*>(lds + (base) + adst1) = make_uint4(w0, w1, w2, w3); \
  }
#define STGB(ktE, base)                                                        \
  {                                                                            \
    __builtin_amdgcn_global_load_lds((gvp)(bS0 + (ktE)),                       \
                                     (lvp)(lds + (base) + bdst0), 16, 0, 0);   \
    __builtin_amdgcn_global_load_lds((gvp)(bS1 + (ktE)),                       \
                                     (lvp)(lds + (base) + bdst1), 16, 0, 0);   \
  }

  // ---- prologue: slots 0..2 staged; leave sa=A(3), sb=A(4) in flight ----
  AISS4(sa, 0);  SB0; CVT4(sa, 0 * SLOT); SB0;
  AISS4(sa, 32); SB0; CVT4(sa, 1 * SLOT); SB0;
  AISS4(sa, 64); SB0; CVT4(sa, 2 * SLOT); SB0;
  STGB(0, 0 * SLOT);
  STGB(32, 1 * SLOT);
  STGB(64, 2 * SLOT);
  AISS4(sa, 96);   // A(3), CVT at t=0
  AISS4(sb, 128);  // A(4), CVT at t=1
  SB0;
  // drain B(0): oldest 2 of [B0(2),B1(2),B2(2),sa(4),sb(4)] = 14 in flight
  asm volatile("s_waitcnt vmcnt(12)" ::: "memory");
  asm volatile("s_waitcnt lgkmcnt(0)" ::: "memory");
  __builtin_amdgcn_s_barrier();
  SB0;

  int rdOff = 0, stOff = 3 * SLOT;

#define TILE(tt, S)                                                          \
  {                                                                          \
    if ((tt) + 3 < NT) CVT4(S, stOff);                                       \
    if ((tt) + 3 < NT) STGB(((tt) + 3) * 32, stOff);                         \
    if ((tt) + 5 < NT) AISS4(S, ((tt) + 5) * 32);                            \
    SB0;                                                                     \
    const char* pA = ldsc + rdOff + offA;                                    \
    const char* pB = ldsc + rdOff + offB;                                    \
    bf16x8 a[8], b[4];                                                       \
    _Pragma("unroll") for (int fi = 0; fi < 8; ++fi)                         \
        a[fi] = *reinterpret_cast<const bf16x8*>(pA + fi * 1024);            \
    _Pragma("unroll") for (int fj = 0; fj < 4; ++fj)                         \
        b[fj] = *reinterpret_cast<const bf16x8*>(pB + fj * 1024);            \
    __builtin_amdgcn_s_setprio(1);                                           \
    _Pragma("unroll") for (int fi = 0; fi < 8; ++fi)                         \
        _Pragma("unroll") for (int fj = 0; fj < 4; ++fj)                     \
            acc[fi][fj] = __builtin_amdgcn_mfma_f32_16x16x32_bf16(           \
                a[fi], b[fj], acc[fi][fj], 0, 0, 0);                         \
    __builtin_amdgcn_s_setprio(0);                                           \
    if ((tt) >= NT - 3 && (tt) < NT - 1) {                                   \
      SB0;                                                                   \
      asm volatile("s_waitcnt vmcnt(0)" ::: "memory");                       \
    }                                                                        \
    __builtin_amdgcn_s_barrier();                                            \
    rdOff = (rdOff == 3 * SLOT) ? 0 : rdOff + SLOT;                          \
    stOff = (stOff == 3 * SLOT) ? 0 : stOff + SLOT;                          \
  }

#pragma unroll 1
  for (int tb = 0; tb < NT; tb += 2) {
    TILE(tb, sa);
    TILE(tb + 1, sb);
  }
#undef TILE
#undef AISS4
#undef CVT4
#undef STGB
#undef SB0

  // ---- epilogue: C/D layout col=lane&15, row=(lane>>4)*4+r ----
#pragma unroll
  for (int fi = 0; fi < 8; ++fi) {
#pragma unroll
    for (int fj = 0; fj < 4; ++fj) {
      int n = bn * 256 + wn * 64 + fj * 16 + lm;
      float bv = bias[n];
#pragma unroll
      for (int r = 0; r < 4; ++r) {
        size_t m = bm * 256 + wm * 128 + fi * 16 + ((lane >> 4) * 4) + r;
        Cg[m * 1024 + n] = f2bf(acc[fi][fj][r] + bv);
      }
    }
  }
}

// ---------------- 128x128 gload_lds GEMM (Q/O; verified) -------------------
template <typename TOUT>
__global__ __launch_bounds__(256) void gemm_lds(const ushort* __restrict__ Ag,
                                                const ushort* __restrict__ Wg,
                                                const float* __restrict__ bias,
                                                TOUT* __restrict__ Cg) {
  constexpr int K = 1024;
  __shared__ ushort lA[128 * 64];
  __shared__ ushort lB[128 * 64];
  const int tid = threadIdx.x;
  const int lane = tid & 63;
  const int wave = tid >> 6;
  const int wr = (wave >> 1) * 64;
  const int wc = (wave & 1) * 64;
  const int d = blockIdx.x;
  const int bn = (d >> 3) & 7;
  const size_t bm = (size_t)(d & 7) * (gridDim.x >> 6) + (d >> 6);

  const ushort* aB = Ag + bm * 128 * K;
  const ushort* bB = Wg + (size_t)bn * 128 * K;
  const int srow = wave * 32 + (lane >> 3);
  const int scol = ((lane & 7) ^ (lane >> 3)) * 8;
  char* lAc = (char*)lA;
  char* lBc = (char*)lB;

  f32x4 acc[4][4] = {};

  for (int kt = 0; kt < K; kt += 64) {
    __syncthreads();
#pragma unroll
    for (int c = 0; c < 4; ++c) {
      __builtin_amdgcn_global_load_lds(
          (gvp)(aB + (size_t)(srow + c * 8) * K + kt + scol),
          (lvp)(lAc + wave * 4096 + c * 1024), 16, 0, 0);
      __builtin_amdgcn_global_load_lds(
          (gvp)(bB + (size_t)(srow + c * 8) * K + kt + scol),
          (lvp)(lBc + wave * 4096 + c * 1024), 16, 0, 0);
    }
    __syncthreads();
#pragma unroll
    for (int kk = 0; kk < 2; ++kk) {
      bf16x8 af[4], bg[4];
#pragma unroll
      for (int fi = 0; fi < 4; ++fi) {
        int r = wr + fi * 16 + (lane & 15);
        int byte = (r * 128 + kk * 64 + ((lane >> 4) * 16)) ^ ((r & 7) << 4);
        af[fi] = *reinterpret_cast<const bf16x8*>(lAc + byte);
      }
#pragma unroll
      for (int fj = 0; fj < 4; ++fj) {
        int r = wc + fj * 16 + (lane & 15);
        int byte = (r * 128 + kk * 64 + ((lane >> 4) * 16)) ^ ((r & 7) << 4);
        bg[fj] = *reinterpret_cast<const bf16x8*>(lBc + byte);
      }
#pragma unroll
      for (int fi = 0; fi < 4; ++fi)
#pragma unroll
        for (int fj = 0; fj < 4; ++fj)
          acc[fi][fj] = __builtin_amdgcn_mfma_f32_16x16x32_bf16(af[fi], bg[fj],
                                                                acc[fi][fj], 0, 0, 0);
    }
  }
#pragma unroll
  for (int fi = 0; fi < 4; ++fi) {
#pragma unroll
    for (int fj = 0; fj < 4; ++fj) {
      int n = bn * 128 + wc + fj * 16 + (lane & 15);
      float bv = bias[n];
#pragma unroll
      for (int r = 0; r < 4; ++r) {
        size_t m = bm * 128 + wr + fi * 16 + ((lane >> 4) * 4) + r;
        float val = acc[fi][fj][r] + bv;
        if constexpr (sizeof(TOUT) == 2)
          reinterpret_cast<ushort*>(Cg)[m * 1024 + n] = f2bf(val);
        else
          reinterpret_cast<float*>(Cg)[m * 1024 + n] = val;
      }
    }
  }
}

// ------------- reg-staged GEMM (fp32 A): fallback path only ---------------
template <typename TIN, typename TOUT>
__global__ __launch_bounds__(256) void gemm_bias(const TIN* __restrict__ Ag,
                                                 const float* __restrict__ Wg,
                                                 const float* __restrict__ bias,
                                                 TOUT* __restrict__ Cg) {
  constexpr int K = 1024;
  __shared__ char lA[128 * 64 * 2];
  __shared__ char lB[128 * 64 * 2];
  const int tid = threadIdx.x;
  const int lane = tid & 63;
  const int wave = tid >> 6;
  const int wr = (wave >> 1) * 64;
  const int wc = (wave & 1) * 64;
  const int bn = blockIdx.x;
  const size_t bm = blockIdx.y;

  const TIN* aBase = Ag + bm * 128 * K;
  const float* bBase = Wg + (size_t)bn * 128 * K;

  f32x4 acc[4][4] = {};

  for (int kt = 0; kt < K; kt += 64) {
    __syncthreads();
    if constexpr (sizeof(TIN) == 4) {
#pragma unroll
      for (int i = 0; i < 8; ++i) {
        int f = tid + i * 256;
        int row = f >> 4, c4 = f & 15;
        const float4 v = *reinterpret_cast<const float4*>(
            reinterpret_cast<const float*>(aBase) + (size_t)row * K + kt + c4 * 4);
        ushort4 pk;
        pk.x = f2bf(v.x); pk.y = f2bf(v.y); pk.z = f2bf(v.z); pk.w = f2bf(v.w);
        int byte = (row * 128 + c4 * 8) ^ ((row & 7) << 4);
        *reinterpret_cast<ushort4*>(lA + byte) = pk;
      }
    } else {
#pragma unroll
      for (int i = 0; i < 4; ++i) {
        int f = tid + i * 256;
        int row = f >> 3, c8 = f & 7;
        int4 v = *reinterpret_cast<const int4*>(
            reinterpret_cast<const ushort*>(aBase) + (size_t)row * K + kt + c8 * 8);
        int byte = (row * 128 + c8 * 16) ^ ((row & 7) << 4);
        *reinterpret_cast<int4*>(lA + byte) = v;
      }
    }
#pragma unroll
    for (int i = 0; i < 8; ++i) {
      int f = tid + i * 256;
      int row = f >> 4, c4 = f & 15;
      const float4 v =
          *reinterpret_cast<const float4*>(bBase + (size_t)row * K + kt + c4 * 4);
      ushort4 pk;
      pk.x = f2bf(v.x); pk.y = f2bf(v.y); pk.z = f2bf(v.z); pk.w = f2bf(v.w);
      int byte = (row * 128 + c4 * 8) ^ ((row & 7) << 4);
      *reinterpret_cast<ushort4*>(lB + byte) = pk;
    }
    __syncthreads();
#pragma unroll
    for (int kk = 0; kk < 2; ++kk) {
      bf16x8 af[4], bg[4];
#pragma unroll
      for (int fi = 0; fi < 4; ++fi) {
        int r = wr + fi * 16 + (lane & 15);
        int byte = (r * 128 + kk * 64 + ((lane >> 4) * 16)) ^ ((r & 7) << 4);
        af[fi] = *reinterpret_cast<const bf16x8*>(lA + byte);
      }
#pragma unroll
      for (int fj = 0; fj < 4; ++fj) {
        int r = wc + fj * 16 + (lane & 15);
        int byte = (r * 128 + kk * 64 + ((lane >> 4) * 16)) ^ ((r & 7) << 4);
        bg[fj] = *reinterpret_cast<const bf16x8*>(lB + byte);
      }
#pragma unroll
      for (int fi = 0; fi < 4; ++fi)
#pragma unroll
        for (int fj = 0; fj < 4; ++fj)
          acc[fi][fj] =
              __builtin_amdgcn_mfma_f32_16x16x32_bf16(af[fi], bg[fj], acc[fi][fj], 0, 0, 0);
    }
  }
#pragma unroll
  for (int fi = 0; fi < 4; ++fi) {
#pragma unroll
    for (int fj = 0; fj < 4; ++fj) {
      int n = bn * 128 + wc + fj * 16 + (lane & 15);
      float bv = bias[n];
#pragma unroll
      for (int r = 0; r < 4; ++r) {
        size_t m = bm * 128 + wr + fi * 16 + ((lane >> 4) * 4) + r;
        float val = acc[fi][fj][r] + bv;
        if constexpr (sizeof(TOUT) == 2)
          reinterpret_cast<ushort*>(Cg)[m * 1024 + n] = f2bf(val);
        else
          reinterpret_cast<float*>(Cg)[m * 1024 + n] = val;
      }
    }
  }
}

// ---------------- attention: one block per (b,s'), head-axis softmax ------
__global__ __launch_bounds__(512) void attn_kernel(const ushort* __restrict__ Q,
                                                   const ushort* __restrict__ Kl,
                                                   const ushort* __restrict__ Vl,
                                                   ushort* __restrict__ Aout) {
  const int bs = blockIdx.x;
  const int b = bs >> 11, sp = bs & 2047;
  const int tid = threadIdx.x;
  const int wave = tid >> 6, lane = tid & 63;

  __shared__ ushort qrow[1024];
  __shared__ float sc[16][32];
  __shared__ float attnw[16][32];
  __shared__ float mx[32], rinv[32];

  reinterpret_cast<uint*>(qrow)[tid] =
      reinterpret_cast<const uint*>(Q + (size_t)bs * 1024)[tid];
  __syncthreads();

  const int wp = lane & 31, half = lane >> 5;
#pragma unroll
  for (int hh = 0; hh < 2; ++hh) {
    const int h = wave * 2 + hh;
    const int s_k = h * 128 + (sp >> 4);
    const int w_k = (sp & 15) * 2 + (wp >> 4);
    const ushort* kp =
        Kl + (((size_t)(b * 2048 + s_k) * 32) + w_k) * 1024 + (wp & 15) * 64 + half * 32;
    const ushort* qp = qrow + h * 64 + half * 32;
    float dot = 0.f;
#pragma unroll
    for (int j = 0; j < 32; j += 8) {
      int4 kv = *reinterpret_cast<const int4*>(kp + j);
      int4 qv = *reinterpret_cast<const int4*>(qp + j);
      const ushort* ka = reinterpret_cast<const ushort*>(&kv);
      const ushort* qa = reinterpret_cast<const ushort*>(&qv);
#pragma unroll
      for (int t = 0; t < 8; ++t) dot += bf2f(ka[t]) * bf2f(qa[t]);
    }
    dot += __shfl_xor(dot, 32);
    if (half == 0) sc[h][wp] = dot * 0.125f;
  }
  __syncthreads();
  if (tid < 32) {
    float m = sc[0][tid];
#pragma unroll
    for (int h = 1; h < 16; ++h) m = fmaxf(m, sc[h][tid]);
    float s = 0.f;
#pragma unroll
    for (int h = 0; h < 16; ++h) s += __expf(sc[h][tid] - m);
    mx[tid] = m;
    rinv[tid] = 1.f / s;
  }
  __syncthreads();
  if (lane < 32) {
#pragma unroll
    for (int hh = 0; hh < 2; ++hh) {
      const int h = wave * 2 + hh;
      attnw[h][lane] = __expf(sc[h][lane] - mx[lane]) * rinv[lane];
    }
  }
  __syncthreads();
#pragma unroll
  for (int hh = 0; hh < 2; ++hh) {
    const int h = wave * 2 + hh;
    const int s_k = h * 128 + (sp >> 4);
    const size_t vb = (((size_t)(b * 2048 + s_k) * 32) + (sp & 15) * 2) * 1024;
    float a = 0.f;
#pragma unroll
    for (int w2 = 0; w2 < 32; ++w2) {
      float wgt = attnw[h][w2];
      a += wgt * bf2f(Vl[vb + (size_t)(w2 >> 4) * 1024 + (w2 & 15) * 64 + lane]);
    }
    Aout[(((size_t)(b * 16 + h)) * 2048 + sp) * 64 + lane] = f2bf(a);
  }
}

extern "C" void kernel_launch(void* const* d_in, const int* in_sizes, int n_in,
                              void* d_out, int out_size, void* d_ws, size_t ws_size,
                              hipStream_t stream) {
  const float* q = (const float*)d_in[0];
  const float* k = (const float*)d_in[1];
  const float* v = (const float*)d_in[2];
  const float* Wq = (const float*)d_in[3];
  const float* bq = (const float*)d_in[4];
  const float* Wk = (const float*)d_in[5];
  const float* bk = (const float*)d_in[6];
  const float* Wv = (const float*)d_in[7];
  const float* bv = (const float*)d_in[8];
  const float* Wo = (const float*)d_in[9];
  const float* bo = (const float*)d_in[10];
  float* out = (float*)d_out;

  char* ws = (char*)d_ws;
  const size_t MB = 1u << 20;
  ushort* Qlin = (ushort*)ws;                    // 8 MiB
  ushort* Aws  = (ushort*)(ws + 8 * MB);         // 8 MiB
  ushort* wkbf = (ushort*)(ws + 16 * MB);        // 2 MiB
  ushort* wvbf = (ushort*)(ws + 18 * MB);        // 2 MiB
  ushort* wqbf = (ushort*)(ws + 20 * MB);        // 2 MiB
  ushort* wobf = (ushort*)(ws + 22 * MB);        // 2 MiB
  ushort* qbf  = (ushort*)(ws + 24 * MB);        // 8 MiB
  ushort* Klin = (ushort*)(ws + 32 * MB);        // 256 MiB
  ushort* Vlin = (ushort*)(ws + 288 * MB);       // 256 MiB
  const bool full = ws_size >= 800 * MB;

  if (full) {
    cast_kernel<<<dim3(512), 256, 0, stream>>>(Wq, wqbf, 1048576L);
    cast_kernel<<<dim3(512), 256, 0, stream>>>(Wk, wkbf, 1048576L);
    cast_kernel<<<dim3(512), 256, 0, stream>>>(Wv, wvbf, 1048576L);
    cast_kernel<<<dim3(512), 256, 0, stream>>>(Wo, wobf, 1048576L);
    cast_kernel<<<dim3(2048), 256, 0, stream>>>(q, qbf, 4194304L);
    gemm_lds<ushort><<<dim3(256), 256, 0, stream>>>(qbf, wqbf, bq, Qlin);
    gemm_big<<<dim3(2048), 512, 0, stream>>>(k, wkbf, bk, Klin);
    gemm_big<<<dim3(2048), 512, 0, stream>>>(v, wvbf, bv, Vlin);
    attn_kernel<<<dim3(4096), dim3(512), 0, stream>>>(Qlin, Klin, Vlin, Aws);
    gemm_lds<float><<<dim3(256), 256, 0, stream>>>(Aws, wobf, bo, out);
  } else {
    gemm_bias<float, ushort><<<dim3(8, 32), 256, 0, stream>>>(q, Wq, bq, Qlin);
    gemm_bias<float, ushort><<<dim3(8, 1024), 256, 0, stream>>>(k, Wk, bk, Klin);
    gemm_bias<float, ushort><<<dim3(8, 1024), 256, 0, stream>>>(v, Wv, bv, Vlin);
    attn_kernel<<<dim3(4096), dim3(512), 0, stream>>>(Qlin, Klin, Vlin, Aws);
    gemm_bias<ushort, float><<<dim3(8, 32), 256, 0, stream>>>(Aws, Wo, bo, out);
  }
}

// Round 10
// 954.886 us; speedup vs baseline: 1.1014x; 1.0150x over previous
//
#include <hip/hip_runtime.h>
#include <hip/hip_bf16.h>

// B=2, S=2048, W=32, D=1024, H=16, hd=64
// Pipeline (full path):
//   bf16-cast: Wq,Wk,Wv,Wo,q (small only)
//   K GEMM: gemm_big_f32 = round-6 verified 8-phase kk-split fused-cast
//           kernel (405us steady) + V-CAST RIDER: per phase each thread
//           moves one float4 of v (fp32 load at ph1/3/5/7, cvt_pk + 8B
//           store at ph2/4/6/8; 1-phase ~1900cyc age >> HBM latency).
//           32 units/thread x 512thr x 2048blk x 16B = 512MiB = all of v.
//           vmcnt soundness: rider ops only make existing counted drains
//           MORE conservative (vmcnt(N) drains all-but-newest-N), so
//           round-6's counts are kept unchanged.
//   V GEMM: gemm_big_bf16 = round-0 verified bf16-input kernel (314us):
//           256x256, BK=32, 4-slot ring, depth-3 prefetch, vmcnt(8).
//   Q/O GEMM: gemm_lds (128x128)
//   attn: per (b,s') head-softmax gather-attention -> A (4096x1024 bf16)
//   out  = A@Wo^T+bo (fp32)

#define DEVI __device__ __forceinline__

typedef __attribute__((ext_vector_type(8))) short bf16x8;
typedef __attribute__((ext_vector_type(4))) float f32x4;
typedef const __attribute__((address_space(1))) void* gvp;
typedef __attribute__((address_space(3))) void* lvp;

DEVI ushort f2bf(float f) {
  uint u = __float_as_uint(f);
  u = u + 0x7fffu + ((u >> 16) & 1u);
  return (ushort)(u >> 16);
}
DEVI float bf2f(ushort u) { return __uint_as_float(((uint)u) << 16); }

// ---------------- elementwise fp32 -> bf16 cast (RNE), 8 elems/thread ----
__global__ __launch_bounds__(256) void cast_kernel(const float* __restrict__ in,
                                                   ushort* __restrict__ out,
                                                   long n) {
  long i = ((long)blockIdx.x * 256 + threadIdx.x) * 8;
  const long stride = (long)gridDim.x * 256 * 8;
  for (; i < n; i += stride) {
    float4 a = *reinterpret_cast<const float4*>(in + i);
    float4 b = *reinterpret_cast<const float4*>(in + i + 4);
    ushort o[8];
    o[0] = f2bf(a.x); o[1] = f2bf(a.y); o[2] = f2bf(a.z); o[3] = f2bf(a.w);
    o[4] = f2bf(b.x); o[5] = f2bf(b.y); o[6] = f2bf(b.z); o[7] = f2bf(b.w);
    *reinterpret_cast<int4*>(out + i) = *reinterpret_cast<const int4*>(o);
  }
}

// ---------------- fused-cast kk-split 8-phase GEMM + V-cast rider ---------
// C = A(fp32) @ W(bf16)^T + bias, bf16 out. Tile 256x256, BK=64, 16 K-tiles,
// 8 iters x 2 tiles. LDS: buf0 { A@0 (A0,A1), B@32K (B0,B1) }, buf1 = +64K.
// Row = 128B = 8 chunks of 16B; stored chunk p of row r holds source chunk
// p^(r&7); fragment read swz ((kk*4+q)^(lm&7))*16. (= round-6, 405us.)
template <int FJ0>
DEVI void mfma16b(f32x4 (&acc)[8][4], const bf16x8 (&A)[8], const bf16x8 (&B)[2]) {
  __builtin_amdgcn_s_setprio(1);
#pragma unroll
  for (int fi = 0; fi < 8; ++fi)
#pragma unroll
    for (int j = 0; j < 2; ++j)
      acc[fi][FJ0 + j] = __builtin_amdgcn_mfma_f32_16x16x32_bf16(
          A[fi], B[j], acc[fi][FJ0 + j], 0, 0, 0);
  __builtin_amdgcn_s_setprio(0);
}

__global__ __launch_bounds__(512)
__attribute__((amdgpu_waves_per_eu(2, 2)))
void gemm_big_f32(const float* __restrict__ Ag, const ushort* __restrict__ Wg,
                  const float* __restrict__ bias, ushort* __restrict__ Cg,
                  const float* __restrict__ Vsrc, ushort* __restrict__ Vbf) {
  constexpr int K = 1024;
  __shared__ char lds[131072];
  const int tid = threadIdx.x;
  const int lane = tid & 63;
  const int wave = tid >> 6;
  const int wm = wave >> 2;
  const int wn = wave & 3;
  const int d = blockIdx.x;
  const int bn = (d >> 3) & 3;
  const size_t bm = (size_t)(d & 7) * (gridDim.x >> 5) + (d >> 5);

  const ushort* bB = Wg + (size_t)bn * 256 * K;

  const int r0 = tid >> 3;
  const int c0 = (tid & 7) ^ (r0 & 7);
  const float* pR0 = Ag + bm * 256 * K + (size_t)r0 * K + c0 * 8;
  const float* pR1 = pR0 + 64 * K;
  const ushort* bS0 = bB + (size_t)r0 * K + c0 * 8;
  const ushort* bS1 = bB + (size_t)(r0 + 64) * K + c0 * 8;
  const ushort* bS2 = bB + (size_t)(r0 + 128) * K + c0 * 8;
  const ushort* bS3 = bB + (size_t)(r0 + 192) * K + c0 * 8;

  const int lm = lane & 15;
  const int q = lane >> 4;
  const int rowB = lm * 128;
  const int swz0 = (q ^ (lm & 7)) * 16;
  const int swz1 = ((4 + q) ^ (lm & 7)) * 16;
  const char* ldsc = (const char*)lds;
  const char* p0A = ldsc + wm * 16384 + rowB;
  const char* p0B = ldsc + 32768 + (wn >> 1) * 16384 + (wn & 1) * 8192 + rowB;
  const char* p1A = p0A + 65536;
  const char* p1B = p0B + 65536;

  // rider: this block casts v[d*65536 .. d*65536+65535] (fp32 -> bf16)
  const float* rsrc = Vsrc + (size_t)d * 65536 + tid * 4;
  ushort* rdst = Vbf + (size_t)d * 65536 + tid * 4;

  f32x4 acc[8][4] = {};
  bf16x8 A8[8];
  bf16x8 Bf[2];
  float4 st[8];
  float4 rv;

#define SB0 __builtin_amdgcn_sched_barrier(0)
#define BAR __builtin_amdgcn_s_barrier()
#define STG(p0, p1, ktE, ldsOff)                                                 \
  {                                                                              \
    __builtin_amdgcn_global_load_lds((gvp)((p0) + (ktE)),                        \
                                     (lvp)(lds + (ldsOff) + tid * 16), 16, 0, 0);\
    __builtin_amdgcn_global_load_lds((gvp)((p1) + (ktE)),                        \
                                     (lvp)(lds + (ldsOff) + 8192 + tid * 16),    \
                                     16, 0, 0);                                  \
  }
#define AISS8(off)                                                      \
  {                                                                     \
    st[0] = *reinterpret_cast<const float4*>(pR0 + (off));              \
    st[1] = *reinterpret_cast<const float4*>(pR0 + (off) + 4);          \
    st[2] = *reinterpret_cast<const float4*>(pR1 + (off));              \
    st[3] = *reinterpret_cast<const float4*>(pR1 + (off) + 4);          \
    st[4] = *reinterpret_cast<const float4*>(pR0 + 131072 + (off));     \
    st[5] = *reinterpret_cast<const float4*>(pR0 + 131072 + (off) + 4); \
    st[6] = *reinterpret_cast<const float4*>(pR1 + 131072 + (off));     \
    st[7] = *reinterpret_cast<const float4*>(pR1 + 131072 + (off) + 4); \
  }
#define CVTPAIR(v0, v1, dstoff)                                              \
  {                                                                          \
    uint w0, w1, w2, w3;                                                     \
    asm("v_cvt_pk_bf16_f32 %0,%1,%2" : "=v"(w0) : "v"((v0).x), "v"((v0).y)); \
    asm("v_cvt_pk_bf16_f32 %0,%1,%2" : "=v"(w1) : "v"((v0).z), "v"((v0).w)); \
    asm("v_cvt_pk_bf16_f32 %0,%1,%2" : "=v"(w2) : "v"((v1).x), "v"((v1).y)); \
    asm("v_cvt_pk_bf16_f32 %0,%1,%2" : "=v"(w3) : "v"((v1).z), "v"((v1).w)); \
    *reinterpret_cast<uint4*>(lds + (dstoff) + tid * 16) =                   \
        make_uint4(w0, w1, w2, w3);                                          \
  }
#define CVT8(base)                          \
  {                                         \
    CVTPAIR(st[0], st[1], (base));          \
    CVTPAIR(st[2], st[3], (base) + 8192);   \
    CVTPAIR(st[4], st[5], (base) + 16384);  \
    CVTPAIR(st[6], st[7], (base) + 24576);  \
  }
#define PH_SYNC()                                    \
  __builtin_amdgcn_s_barrier();                      \
  asm volatile("s_waitcnt lgkmcnt(0)" ::: "memory"); \
  SB0;
#define LDA8(p, swz)                                                       \
  _Pragma("unroll") for (int i_ = 0; i_ < 8; ++i_) {                       \
    A8[i_] = *reinterpret_cast<const bf16x8*>((p) + i_ * 2048 + (swz));    \
  }
#define LDB2(p, fjb, swz)                                                  \
  {                                                                        \
    Bf[0] = *reinterpret_cast<const bf16x8*>((p) + (fjb) + (swz));         \
    Bf[1] = *reinterpret_cast<const bf16x8*>((p) + (fjb) + 2048 + (swz));  \
  }
#define RLD(u) { rv = *reinterpret_cast<const float4*>(rsrc + (size_t)(u) * 2048); }
#define RST(u)                                                               \
  {                                                                          \
    uint w0, w1;                                                             \
    asm("v_cvt_pk_bf16_f32 %0,%1,%2" : "=v"(w0) : "v"(rv.x), "v"(rv.y));     \
    asm("v_cvt_pk_bf16_f32 %0,%1,%2" : "=v"(w1) : "v"(rv.z), "v"(rv.w));     \
    *reinterpret_cast<uint2*>(rdst + (size_t)(u) * 2048) = make_uint2(w0, w1);\
  }

  // ---- prologue: buf0 <- tile0 (A cvt + B stg); leave st = A(1) in flight.
  AISS8(0); SB0;
  CVT8(0);  // auto-wait vmcnt(0); writes buf0.A(tile0)
  SB0;
  STG(bS0, bS1, 0, 32768); STG(bS2, bS3, 0, 49152); SB0;
  AISS8(64); SB0;  // A(1) -> consumed at it0 ph2 CVT
  asm volatile("s_waitcnt vmcnt(8)" ::: "memory");  // drain B(0), keep st
  asm volatile("s_waitcnt lgkmcnt(0)" ::: "memory");
  BAR;
  SB0;

#define ITER(M)                                                           \
  {                                                                       \
    const int ktB1 = (2 * it + 1) * 64;                                   \
    const int ktB2 = (2 * it + 2) * 64;                                   \
    const int ktA2 = (2 * it + 2) * 64;                                   \
    const int ktA3 = (2 * it + 3) * 64;                                   \
    /* ph1: buf0 kk0 fj01; stage BOTH B(j+1) halves -> buf1.B */          \
    LDA8(p0A, swz0); LDB2(p0B, 0, swz0);                                  \
    STG(bS0, bS1, ktB1, 98304); STG(bS2, bS3, ktB1, 114688);              \
    RLD(it * 4 + 0);                                                      \
    PH_SYNC(); mfma16b<0>(acc, A8, Bf); BAR;                              \
    /* ph2: buf0 kk0 fj23; CVT st -> buf1.A(j+1); AISS st <- A(j+2) */    \
    LDB2(p0B, 4096, swz0);                                                \
    CVT8(65536);                                                          \
    SB0;                                                                  \
    if (M == 0) { AISS8(ktA2); SB0; }                                     \
    RST(it * 4 + 0);                                                      \
    PH_SYNC(); mfma16b<2>(acc, A8, Bf); BAR;                              \
    /* ph3: buf0 kk1 fj01 */                                              \
    LDA8(p0A, swz1); LDB2(p0B, 0, swz1);                                  \
    RLD(it * 4 + 1);                                                      \
    PH_SYNC(); mfma16b<0>(acc, A8, Bf); BAR;                              \
    /* ph4: buf0 kk1 fj23; end: counted drain for B(j+1) */               \
    LDB2(p0B, 4096, swz1);                                                \
    RST(it * 4 + 1);                                                      \
    PH_SYNC(); mfma16b<2>(acc, A8, Bf);                                   \
    SB0;                                                                  \
    if (M == 0) { asm volatile("s_waitcnt vmcnt(8)" ::: "memory"); }      \
    else        { asm volatile("s_waitcnt vmcnt(0)" ::: "memory"); }      \
    BAR; SB0;                                                             \
    /* ph5: buf1 kk0 fj01; stage BOTH B(j+2) halves -> buf0.B */          \
    LDA8(p1A, swz0); LDB2(p1B, 0, swz0);                                  \
    if (M == 0) { STG(bS0, bS1, ktB2, 32768); STG(bS2, bS3, ktB2, 49152); } \
    RLD(it * 4 + 2);                                                      \
    PH_SYNC(); mfma16b<0>(acc, A8, Bf); BAR;                              \
    /* ph6: buf1 kk0 fj23; CVT st -> buf0.A(j+2); AISS st <- A(j+3) */    \
    LDB2(p1B, 4096, swz0);                                                \
    if (M == 0) { CVT8(0); SB0; AISS8(ktA3); SB0; }                       \
    RST(it * 4 + 2);                                                      \
    PH_SYNC(); mfma16b<2>(acc, A8, Bf); BAR;                              \
    /* ph7: buf1 kk1 fj01 */                                              \
    LDA8(p1A, swz1); LDB2(p1B, 0, swz1);                                  \
    RLD(it * 4 + 3);                                                      \
    PH_SYNC(); mfma16b<0>(acc, A8, Bf); BAR;                              \
    /* ph8: buf1 kk1 fj23; end: counted drain for B(j+2) */               \
    LDB2(p1B, 4096, swz1);                                                \
    RST(it * 4 + 3);                                                      \
    PH_SYNC(); mfma16b<2>(acc, A8, Bf);                                   \
    if (M == 0) {                                                         \
      SB0;                                                                \
      asm volatile("s_waitcnt vmcnt(8)" ::: "memory");                    \
      BAR; SB0;                                                           \
    }                                                                     \
  }

#pragma unroll 1
  for (int it = 0; it < 7; ++it) ITER(0);
  { const int it = 7; ITER(1); }
#undef ITER
#undef STG
#undef AISS8
#undef CVTPAIR
#undef CVT8
#undef PH_SYNC
#undef LDA8
#undef LDB2
#undef RLD
#undef RST
#undef SB0
#undef BAR

  // ---- epilogue: C/D layout col=lane&15, row=(lane>>4)*4+r ----
#pragma unroll
  for (int fi = 0; fi < 8; ++fi) {
#pragma unroll
    for (int fj = 0; fj < 4; ++fj) {
      int n = bn * 256 + wn * 64 + fj * 16 + lm;
      float bv = bias[n];
#pragma unroll
      for (int r = 0; r < 4; ++r) {
        size_t m = bm * 256 + wm * 128 + fi * 16 + ((lane >> 4) * 4) + r;
        Cg[m * 1024 + n] = f2bf(acc[fi][fj][r] + bv);
      }
    }
  }
}

// ---------------- bf16-input deep-pipelined GEMM (round-0, 314us) ---------
// C = A(bf16) @ W(bf16)^T + bias (bf16 out). Tile 256x256, K=1024, BK=32,
// 4-slot LDS ring, depth-3 prefetch, counted vmcnt(8), chunk-XOR swizzle.
__global__ __launch_bounds__(512, 2) void gemm_big_bf16(const ushort* __restrict__ Ag,
                                                        const ushort* __restrict__ Wg,
                                                        const float* __restrict__ bias,
                                                        ushort* __restrict__ Cg) {
  constexpr int K = 1024;
  constexpr int NT = 32;
  constexpr int SLOT = 32768;
  __shared__ char lds[4 * SLOT];
  const int tid = threadIdx.x;
  const int lane = tid & 63;
  const int wave = tid >> 6;
  const int wm = wave >> 2;
  const int wn = wave & 3;
  const int d = blockIdx.x;
  const int bn = (d >> 3) & 3;
  const size_t bm = (size_t)(d & 7) * (gridDim.x >> 5) + (d >> 5);

  const ushort* aB = Ag + bm * 256 * K;
  const ushort* bB = Wg + (size_t)bn * 256 * K;

  const int ar0 = tid >> 2, ac0 = (tid & 3) ^ ((ar0 >> 1) & 3);
  const int ar1 = (tid + 512) >> 2, ac1 = (tid & 3) ^ ((ar1 >> 1) & 3);
  const ushort* aS0 = aB + (size_t)ar0 * K + ac0 * 8;
  const ushort* aS1 = aB + (size_t)ar1 * K + ac1 * 8;
  const ushort* bS0 = bB + (size_t)ar0 * K + ac0 * 8;
  const ushort* bS1 = bB + (size_t)ar1 * K + ac1 * 8;
  const int adst0 = tid * 16;
  const int adst1 = tid * 16 + 8192;
  const int bdst0 = 16384 + tid * 16;
  const int bdst1 = 24576 + tid * 16;

  const int lm = lane & 15;
  const int cs = (lm >> 1) & 3;
  const int cSwz = ((lane >> 4) ^ cs) * 16;
  const int offA = lm * 64 + cSwz + wm * 8192;
  const int offB = 16384 + lm * 64 + cSwz + wn * 4096;

  f32x4 acc[8][4] = {};

#define STAGE_T(slotOff, ktElem)                                                   \
  {                                                                                \
    __builtin_amdgcn_global_load_lds((gvp)(aS0 + (ktElem)),                        \
                                     (lvp)(lds + (slotOff) + adst0), 16, 0, 0);    \
    __builtin_amdgcn_global_load_lds((gvp)(aS1 + (ktElem)),                        \
                                     (lvp)(lds + (slotOff) + adst1), 16, 0, 0);    \
    __builtin_amdgcn_global_load_lds((gvp)(bS0 + (ktElem)),                        \
                                     (lvp)(lds + (slotOff) + bdst0), 16, 0, 0);    \
    __builtin_amdgcn_global_load_lds((gvp)(bS1 + (ktElem)),                        \
                                     (lvp)(lds + (slotOff) + bdst1), 16, 0, 0);    \
  }

  STAGE_T(0 * SLOT, 0);
  STAGE_T(1 * SLOT, 32);
  STAGE_T(2 * SLOT, 64);
  __builtin_amdgcn_sched_barrier(0);
  asm volatile("s_waitcnt vmcnt(8)" ::: "memory");
  __builtin_amdgcn_s_barrier();
  __builtin_amdgcn_sched_barrier(0);

  int rdOff = 0, stOff = 3 * SLOT;
  for (int t = 0; t < NT; ++t) {
    if (t + 3 < NT) STAGE_T(stOff, (t + 3) * 32);
    const char* pA = (const char*)lds + rdOff + offA;
    const char* pB = (const char*)lds + rdOff + offB;
    bf16x8 a[8], b[4];
#pragma unroll
    for (int fi = 0; fi < 8; ++fi)
      a[fi] = *reinterpret_cast<const bf16x8*>(pA + fi * 1024);
#pragma unroll
    for (int fj = 0; fj < 4; ++fj)
      b[fj] = *reinterpret_cast<const bf16x8*>(pB + fj * 1024);
    __builtin_amdgcn_s_setprio(1);
#pragma unroll
    for (int fi = 0; fi < 8; ++fi)
#pragma unroll
      for (int fj = 0; fj < 4; ++fj)
        acc[fi][fj] = __builtin_amdgcn_mfma_f32_16x16x32_bf16(a[fi], b[fj],
                                                              acc[fi][fj], 0, 0, 0);
    __builtin_amdgcn_s_setprio(0);
    if (t < NT - 1) {
      __builtin_amdgcn_sched_barrier(0);
      if (t <= NT - 4)
        asm volatile("s_waitcnt vmcnt(8)" ::: "memory");
      else if (t == NT - 3)
        asm volatile("s_waitcnt vmcnt(4)" ::: "memory");
      else
        asm volatile("s_waitcnt vmcnt(0)" ::: "memory");
      __builtin_amdgcn_s_barrier();
      __builtin_amdgcn_sched_barrier(0);
    }
    rdOff = (rdOff == 3 * SLOT) ? 0 : rdOff + SLOT;
    stOff = (stOff == 3 * SLOT) ? 0 : stOff + SLOT;
  }
#undef STAGE_T

#pragma unroll
  for (int fi = 0; fi < 8; ++fi) {
#pragma unroll
    for (int fj = 0; fj < 4; ++fj) {
      int n = bn * 256 + wn * 64 + fj * 16 + lm;
      float bv = bias[n];
#pragma unroll
      for (int r = 0; r < 4; ++r) {
        size_t m = bm * 256 + wm * 128 + fi * 16 + ((lane >> 4) * 4) + r;
        Cg[m * 1024 + n] = f2bf(acc[fi][fj][r] + bv);
      }
    }
  }
}

// ---------------- 128x128 gload_lds GEMM (Q/O; verified) -------------------
template <typename TOUT>
__global__ __launch_bounds__(256) void gemm_lds(const ushort* __restrict__ Ag,
                                                const ushort* __restrict__ Wg,
                                                const float* __restrict__ bias,
                                                TOUT* __restrict__ Cg) {
  constexpr int K = 1024;
  __shared__ ushort lA[128 * 64];
  __shared__ ushort lB[128 * 64];
  const int tid = threadIdx.x;
  const int lane = tid & 63;
  const int wave = tid >> 6;
  const int wr = (wave >> 1) * 64;
  const int wc = (wave & 1) * 64;
  const int d = blockIdx.x;
  const int bn = (d >> 3) & 7;
  const size_t bm = (size_t)(d & 7) * (gridDim.x >> 6) + (d >> 6);

  const ushort* aB = Ag + bm * 128 * K;
  const ushort* bB = Wg + (size_t)bn * 128 * K;
  const int srow = wave * 32 + (lane >> 3);
  const int scol = ((lane & 7) ^ (lane >> 3)) * 8;
  char* lAc = (char*)lA;
  char* lBc = (char*)lB;

  f32x4 acc[4][4] = {};

  for (int kt = 0; kt < K; kt += 64) {
    __syncthreads();
#pragma unroll
    for (int c = 0; c < 4; ++c) {
      __builtin_amdgcn_global_load_lds(
          (gvp)(aB + (size_t)(srow + c * 8) * K + kt + scol),
          (lvp)(lAc + wave * 4096 + c * 1024), 16, 0, 0);
      __builtin_amdgcn_global_load_lds(
          (gvp)(bB + (size_t)(srow + c * 8) * K + kt + scol),
          (lvp)(lBc + wave * 4096 + c * 1024), 16, 0, 0);
    }
    __syncthreads();
#pragma unroll
    for (int kk = 0; kk < 2; ++kk) {
      bf16x8 af[4], bg[4];
#pragma unroll
      for (int fi = 0; fi < 4; ++fi) {
        int r = wr + fi * 16 + (lane & 15);
        int byte = (r * 128 + kk * 64 + ((lane >> 4) * 16)) ^ ((r & 7) << 4);
        af[fi] = *reinterpret_cast<const bf16x8*>(lAc + byte);
      }
#pragma unroll
      for (int fj = 0; fj < 4; ++fj) {
        int r = wc + fj * 16 + (lane & 15);
        int byte = (r * 128 + kk * 64 + ((lane >> 4) * 16)) ^ ((r & 7) << 4);
        bg[fj] = *reinterpret_cast<const bf16x8*>(lBc + byte);
      }
#pragma unroll
      for (int fi = 0; fi < 4; ++fi)
#pragma unroll
        for (int fj = 0; fj < 4; ++fj)
          acc[fi][fj] = __builtin_amdgcn_mfma_f32_16x16x32_bf16(af[fi], bg[fj],
                                                                acc[fi][fj], 0, 0, 0);
    }
  }
#pragma unroll
  for (int fi = 0; fi < 4; ++fi) {
#pragma unroll
    for (int fj = 0; fj < 4; ++fj) {
      int n = bn * 128 + wc + fj * 16 + (lane & 15);
      float bv = bias[n];
#pragma unroll
      for (int r = 0; r < 4; ++r) {
        size_t m = bm * 128 + wr + fi * 16 + ((lane >> 4) * 4) + r;
        float val = acc[fi][fj][r] + bv;
        if constexpr (sizeof(TOUT) == 2)
          reinterpret_cast<ushort*>(Cg)[m * 1024 + n] = f2bf(val);
        else
          reinterpret_cast<float*>(Cg)[m * 1024 + n] = val;
      }
    }
  }
}

// ------------- reg-staged GEMM (fp32 A): fallback path only ---------------
template <typename TIN, typename TOUT>
__global__ __launch_bounds__(256) void gemm_bias(const TIN* __restrict__ Ag,
                                                 const float* __restrict__ Wg,
                                                 const float* __restrict__ bias,
                                                 TOUT* __restrict__ Cg) {
  constexpr int K = 1024;
  __shared__ char lA[128 * 64 * 2];
  __shared__ char lB[128 * 64 * 2];
  const int tid = threadIdx.x;
  const int lane = tid & 63;
  const int wave = tid >> 6;
  const int wr = (wave >> 1) * 64;
  const int wc = (wave & 1) * 64;
  const int bn = blockIdx.x;
  const size_t bm = blockIdx.y;

  const TIN* aBase = Ag + bm * 128 * K;
  const float* bBase = Wg + (size_t)bn * 128 * K;

  f32x4 acc[4][4] = {};

  for (int kt = 0; kt < K; kt += 64) {
    __syncthreads();
    if constexpr (sizeof(TIN) == 4) {
#pragma unroll
      for (int i = 0; i < 8; ++i) {
        int f = tid + i * 256;
        int row = f >> 4, c4 = f & 15;
        const float4 v = *reinterpret_cast<const float4*>(
            reinterpret_cast<const float*>(aBase) + (size_t)row * K + kt + c4 * 4);
        ushort4 pk;
        pk.x = f2bf(v.x); pk.y = f2bf(v.y); pk.z = f2bf(v.z); pk.w = f2bf(v.w);
        int byte = (row * 128 + c4 * 8) ^ ((row & 7) << 4);
        *reinterpret_cast<ushort4*>(lA + byte) = pk;
      }
    } else {
#pragma unroll
      for (int i = 0; i < 4; ++i) {
        int f = tid + i * 256;
        int row = f >> 3, c8 = f & 7;
        int4 v = *reinterpret_cast<const int4*>(
            reinterpret_cast<const ushort*>(aBase) + (size_t)row * K + kt + c8 * 8);
        int byte = (row * 128 + c8 * 16) ^ ((row & 7) << 4);
        *reinterpret_cast<int4*>(lA + byte) = v;
      }
    }
#pragma unroll
    for (int i = 0; i < 8; ++i) {
      int f = tid + i * 256;
      int row = f >> 4, c4 = f & 15;
      const float4 v =
          *reinterpret_cast<const float4*>(bBase + (size_t)row * K + kt + c4 * 4);
      ushort4 pk;
      pk.x = f2bf(v.x); pk.y = f2bf(v.y); pk.z = f2bf(v.z); pk.w = f2bf(v.w);
      int byte = (row * 128 + c4 * 8) ^ ((row & 7) << 4);
      *reinterpret_cast<ushort4*>(lB + byte) = pk;
    }
    __syncthreads();
#pragma unroll
    for (int kk = 0; kk < 2; ++kk) {
      bf16x8 af[4], bg[4];
#pragma unroll
      for (int fi = 0; fi < 4; ++fi) {
        int r = wr + fi * 16 + (lane & 15);
        int byte = (r * 128 + kk * 64 + ((lane >> 4) * 16)) ^ ((r & 7) << 4);
        af[fi] = *reinterpret_cast<const bf16x8*>(lA + byte);
      }
#pragma unroll
      for (int fj = 0; fj < 4; ++fj) {
        int r = wc + fj * 16 + (lane & 15);
        int byte = (r * 128 + kk * 64 + ((lane >> 4) * 16)) ^ ((r & 7) << 4);
        bg[fj] = *reinterpret_cast<const bf16x8*>(lB + byte);
      }
#pragma unroll
      for (int fi = 0; fi < 4; ++fi)
#pragma unroll
        for (int fj = 0; fj < 4; ++fj)
          acc[fi][fj] =
              __builtin_amdgcn_mfma_f32_16x16x32_bf16(af[fi], bg[fj], acc[fi][fj], 0, 0, 0);
    }
  }
#pragma unroll
  for (int fi = 0; fi < 4; ++fi) {
#pragma unroll
    for (int fj = 0; fj < 4; ++fj) {
      int n = bn * 128 + wc + fj * 16 + (lane & 15);
      float bv = bias[n];
#pragma unroll
      for (int r = 0; r < 4; ++r) {
        size_t m = bm * 128 + wr + fi * 16 + ((lane >> 4) * 4) + r;
        float val = acc[fi][fj][r] + bv;
        if constexpr (sizeof(TOUT) == 2)
          reinterpret_cast<ushort*>(Cg)[m * 1024 + n] = f2bf(val);
        else
          reinterpret_cast<float*>(Cg)[m * 1024 + n] = val;
      }
    }
  }
}

// ---------------- attention: one block per (b,s'), head-axis softmax ------
__global__ __launch_bounds__(512) void attn_kernel(const ushort* __restrict__ Q,
                                                   const ushort* __restrict__ Kl,
                                                   const ushort* __restrict__ Vl,
                                                   ushort* __restrict__ Aout) {
  const int bs = blockIdx.x;
  const int b = bs >> 11, sp = bs & 2047;
  const int tid = threadIdx.x;
  const int wave = tid >> 6, lane = tid & 63;

  __shared__ ushort qrow[1024];
  __shared__ float sc[16][32];
  __shared__ float attnw[16][32];
  __shared__ float mx[32], rinv[32];

  reinterpret_cast<uint*>(qrow)[tid] =
      reinterpret_cast<const uint*>(Q + (size_t)bs * 1024)[tid];
  __syncthreads();

  const int wp = lane & 31, half = lane >> 5;
#pragma unroll
  for (int hh = 0; hh < 2; ++hh) {
    const int h = wave * 2 + hh;
    const int s_k = h * 128 + (sp >> 4);
    const int w_k = (sp & 15) * 2 + (wp >> 4);
    const ushort* kp =
        Kl + (((size_t)(b * 2048 + s_k) * 32) + w_k) * 1024 + (wp & 15) * 64 + half * 32;
    const ushort* qp = qrow + h * 64 + half * 32;
    float dot = 0.f;
#pragma unroll
    for (int j = 0; j < 32; j += 8) {
      int4 kv = *reinterpret_cast<const int4*>(kp + j);
      int4 qv = *reinterpret_cast<const int4*>(qp + j);
      const ushort* ka = reinterpret_cast<const ushort*>(&kv);
      const ushort* qa = reinterpret_cast<const ushort*>(&qv);
#pragma unroll
      for (int t = 0; t < 8; ++t) dot += bf2f(ka[t]) * bf2f(qa[t]);
    }
    dot += __shfl_xor(dot, 32);
    if (half == 0) sc[h][wp] = dot * 0.125f;
  }
  __syncthreads();
  if (tid < 32) {
    float m = sc[0][tid];
#pragma unroll
    for (int h = 1; h < 16; ++h) m = fmaxf(m, sc[h][tid]);
    float s = 0.f;
#pragma unroll
    for (int h = 0; h < 16; ++h) s += __expf(sc[h][tid] - m);
    mx[tid] = m;
    rinv[tid] = 1.f / s;
  }
  __syncthreads();
  if (lane < 32) {
#pragma unroll
    for (int hh = 0; hh < 2; ++hh) {
      const int h = wave * 2 + hh;
      attnw[h][lane] = __expf(sc[h][lane] - mx[lane]) * rinv[lane];
    }
  }
  __syncthreads();
#pragma unroll
  for (int hh = 0; hh < 2; ++hh) {
    const int h = wave * 2 + hh;
    const int s_k = h * 128 + (sp >> 4);
    const size_t vb = (((size_t)(b * 2048 + s_k) * 32) + (sp & 15) * 2) * 1024;
    float a = 0.f;
#pragma unroll
    for (int w2 = 0; w2 < 32; ++w2) {
      float wgt = attnw[h][w2];
      a += wgt * bf2f(Vl[vb + (size_t)(w2 >> 4) * 1024 + (w2 & 15) * 64 + lane]);
    }
    Aout[(((size_t)(b * 16 + h)) * 2048 + sp) * 64 + lane] = f2bf(a);
  }
}

extern "C" void kernel_launch(void* const* d_in, const int* in_sizes, int n_in,
                              void* d_out, int out_size, void* d_ws, size_t ws_size,
                              hipStream_t stream) {
  const float* q = (const float*)d_in[0];
  const float* k = (const float*)d_in[1];
  const float* v = (const float*)d_in[2];
  const float* Wq = (const float*)d_in[3];
  const float* bq = (const float*)d_in[4];
  const float* Wk = (const float*)d_in[5];
  const float* bk = (const float*)d_in[6];
  const float* Wv = (const float*)d_in[7];
  const float* bv = (const float*)d_in[8];
  const float* Wo = (const float*)d_in[9];
  const float* bo = (const float*)d_in[10];
  float* out = (float*)d_out;

  char* ws = (char*)d_ws;
  const size_t MB = 1u << 20;
  ushort* Qlin = (ushort*)ws;                    // 8 MiB
  ushort* Aws  = (ushort*)(ws + 8 * MB);         // 8 MiB
  ushort* wkbf = (ushort*)(ws + 16 * MB);        // 2 MiB
  ushort* wvbf = (ushort*)(ws + 18 * MB);        // 2 MiB
  ushort* wqbf = (ushort*)(ws + 20 * MB);        // 2 MiB
  ushort* wobf = (ushort*)(ws + 22 * MB);        // 2 MiB
  ushort* qbf  = (ushort*)(ws + 24 * MB);        // 8 MiB
  ushort* Klin = (ushort*)(ws + 32 * MB);        // 256 MiB
  ushort* Vlin = (ushort*)(ws + 288 * MB);       // 256 MiB
  ushort* vbf  = (ushort*)(ws + 544 * MB);       // 256 MiB (rider output)
  const bool full = ws_size >= 800 * MB;

  if (full) {
    cast_kernel<<<dim3(512), 256, 0, stream>>>(Wq, wqbf, 1048576L);
    cast_kernel<<<dim3(512), 256, 0, stream>>>(Wk, wkbf, 1048576L);
    cast_kernel<<<dim3(512), 256, 0, stream>>>(Wv, wvbf, 1048576L);
    cast_kernel<<<dim3(512), 256, 0, stream>>>(Wo, wobf, 1048576L);
    cast_kernel<<<dim3(2048), 256, 0, stream>>>(q, qbf, 4194304L);
    gemm_lds<ushort><<<dim3(256), 256, 0, stream>>>(qbf, wqbf, bq, Qlin);
    // K GEMM (fp32 k, fused cast) + V-cast rider -> vbf
    gemm_big_f32<<<dim3(2048), 512, 0, stream>>>(k, wkbf, bk, Klin, v, vbf);
    // V GEMM on pre-cast bf16 (round-0 kernel, 314us)
    gemm_big_bf16<<<dim3(2048), 512, 0, stream>>>(vbf, wvbf, bv, Vlin);
    attn_kernel<<<dim3(4096), dim3(512), 0, stream>>>(Qlin, Klin, Vlin, Aws);
    gemm_lds<float><<<dim3(256), 256, 0, stream>>>(Aws, wobf, bo, out);
  } else {
    gemm_bias<float, ushort><<<dim3(8, 32), 256, 0, stream>>>(q, Wq, bq, Qlin);
    gemm_bias<float, ushort><<<dim3(8, 1024), 256, 0, stream>>>(k, Wk, bk, Klin);
    gemm_bias<float, ushort><<<dim3(8, 1024), 256, 0, stream>>>(v, Wv, bv, Vlin);
    attn_kernel<<<dim3(4096), dim3(512), 0, stream>>>(Qlin, Klin, Vlin, Aws);
    gemm_bias<ushort, float><<<dim3(8, 32), 256, 0, stream>>>(Aws, Wo, bo, out);
  }
}